// Round 1
// baseline (12159.350 us; speedup 1.0000x reference)
//
#include <hip/hip_runtime.h>
#include <hip/hip_bf16.h>
#include <math.h>

// Problem constants
// B=32 S=256 E=300 H=256(4H=1024) L=4000 D=256 G=512 V=50000 LIN1=512 LIN2=256, 2H=512

// ---------------------------------------------------------------------------
// Generic tiled fp32 GEMM: C[M,N] = A[M,K] * B + epilogue
//   BT=true : B is [N][K] row-major (dot over contiguous k)  -> C=A*B^T style
//   BT=false: B is [K][N] row-major
//   GATHER  : A row m comes from A + tok[m]*lda  (embedding gather)
// Epilogue (runtime): + bias[n], + addrow[(m%addmod)*ldadd + n], relu
// Tile: BM=64, BN=128, BK=16, 256 threads, each thread 4(m)x8(n)
// ---------------------------------------------------------------------------
template<bool BT, bool GATHER>
__global__ __launch_bounds__(256) void gemm_k(
    const float* __restrict__ A, const float* __restrict__ Bm, float* __restrict__ C,
    int M, int N, int K, int lda, int ldb, int ldc,
    long abs_, long bbs_, long cbs_,
    const int* __restrict__ tok,
    const float* __restrict__ bias,
    const float* __restrict__ addrow, int addmod, int ldadd,
    int do_relu)
{
    const int tid = threadIdx.x;
    const int tx = tid & 15;        // n dim: 16 threads x 8 cols
    const int ty = tid >> 4;        // m dim: 16 threads x 4 rows
    const int n0 = blockIdx.x * 128;
    const int m0 = blockIdx.y * 64;
    const int z  = blockIdx.z;
    A  += (size_t)z * abs_;
    Bm += (size_t)z * bbs_;
    C  += (size_t)z * cbs_;

    __shared__ float As[16][68];    // [k][m], row = 272B (16B aligned)
    __shared__ float Bs[16][132];   // [k][n], row = 528B (16B aligned)

    float acc[4][8];
#pragma unroll
    for (int i = 0; i < 4; ++i)
#pragma unroll
        for (int j = 0; j < 8; ++j) acc[i][j] = 0.f;

    const int ksteps = (K + 15) / 16;
    for (int kt = 0; kt < ksteps; ++kt) {
        const int k0 = kt * 16;
        // stage A tile (64m x 16k)
#pragma unroll
        for (int j = 0; j < 4; ++j) {
            int e  = tid + j * 256;
            int kk = e & 15;
            int m  = e >> 4;
            int gm = m0 + m, gk = k0 + kk;
            float v = 0.f;
            if (gm < M && gk < K) {
                size_t rb;
                if (GATHER) rb = (size_t)tok[gm] * lda;
                else        rb = (size_t)gm * lda;
                v = A[rb + gk];
            }
            As[kk][m] = v;
        }
        // stage B tile (16k x 128n)
#pragma unroll
        for (int j = 0; j < 8; ++j) {
            int e = tid + j * 256;
            if (BT) {
                int kk = e & 15;
                int n  = e >> 4;
                int gn = n0 + n, gk = k0 + kk;
                Bs[kk][n] = (gn < N && gk < K) ? Bm[(size_t)gn * ldb + gk] : 0.f;
            } else {
                int n  = e & 127;
                int kk = e >> 7;
                int gn = n0 + n, gk = k0 + kk;
                Bs[kk][n] = (gn < N && gk < K) ? Bm[(size_t)gk * ldb + gn] : 0.f;
            }
        }
        __syncthreads();
#pragma unroll
        for (int kk = 0; kk < 16; ++kk) {
            const float4 av  = *(const float4*)&As[kk][ty * 4];
            const float4 b0v = *(const float4*)&Bs[kk][tx * 8];
            const float4 b1v = *(const float4*)&Bs[kk][tx * 8 + 4];
            const float a_[4] = {av.x, av.y, av.z, av.w};
            const float b_[8] = {b0v.x, b0v.y, b0v.z, b0v.w, b1v.x, b1v.y, b1v.z, b1v.w};
#pragma unroll
            for (int i = 0; i < 4; ++i)
#pragma unroll
                for (int j = 0; j < 8; ++j) acc[i][j] = fmaf(a_[i], b_[j], acc[i][j]);
        }
        __syncthreads();
    }

#pragma unroll
    for (int i = 0; i < 4; ++i) {
        const int gm = m0 + ty * 4 + i;
        if (gm >= M) continue;
        const float* addp = addrow ? (addrow + (size_t)(gm % addmod) * ldadd) : nullptr;
#pragma unroll
        for (int j = 0; j < 8; ++j) {
            const int gn = n0 + tx * 8 + j;
            if (gn >= N) continue;
            float v = acc[i][j];
            if (bias) v += bias[gn];
            if (addp) v += addp[gn];
            if (do_relu) v = fmaxf(v, 0.f);
            C[(size_t)gm * ldc + gn] = v;
        }
    }
}

// ---------------------------------------------------------------------------
// biLSTM scan. grid=(32 batches, 2 dirs), 1024 threads.
// Thread t owns gate row t (of 4H=1024); h state in LDS; c in registers of t<256.
// ---------------------------------------------------------------------------
__global__ __launch_bounds__(1024) void lstm_k(
    const float* __restrict__ gxf, const float* __restrict__ gxb,
    const float* __restrict__ whf, const float* __restrict__ whb,
    float* __restrict__ rnn)
{
    const int b = blockIdx.x, dir = blockIdx.y;
    const float* xg = dir ? gxb : gxf;
    const float* W  = dir ? whb : whf;
    __shared__ float h_lds[256];
    __shared__ float g_lds[1024];
    const int t = threadIdx.x;
    if (t < 256) h_lds[t] = 0.f;
    float c = 0.f;
    __syncthreads();
    const float* wrow = W + (size_t)t * 256;
    for (int st = 0; st < 256; ++st) {
        const int ts = dir ? (255 - st) : st;
        float acc = 0.f;
#pragma unroll 8
        for (int k = 0; k < 256; k += 4) {
            const float4 hv = *(const float4*)&h_lds[k];
            const float4 wv = *(const float4*)&wrow[k];
            acc = fmaf(wv.x, hv.x, acc);
            acc = fmaf(wv.y, hv.y, acc);
            acc = fmaf(wv.z, hv.z, acc);
            acc = fmaf(wv.w, hv.w, acc);
        }
        g_lds[t] = acc + xg[((size_t)b * 256 + ts) * 1024 + t];
        __syncthreads();
        if (t < 256) {
            const float gi = g_lds[t];
            const float gf = g_lds[256 + t];
            const float gg = g_lds[512 + t];
            const float go = g_lds[768 + t];
            const float si = 1.f / (1.f + expf(-gi));
            const float sf = 1.f / (1.f + expf(-gf));
            const float so = 1.f / (1.f + expf(-go));
            c = sf * c + si * tanhf(gg);
            const float hn = so * tanhf(c);
            h_lds[t] = hn;  // safe: this step's dots completed before first barrier
            rnn[((size_t)b * 256 + ts) * 512 + (size_t)dir * 256 + t] = hn;
        }
        __syncthreads();
    }
}

// ---------------------------------------------------------------------------
// Masked softmax over s (256) per (bb,l) row, in place. grid=(1000, nb), 256 thr.
// One wave per row; lane holds 4 values.
// ---------------------------------------------------------------------------
__global__ __launch_bounds__(256) void softmax_k(
    float* __restrict__ sc, const int* __restrict__ tokens, int b0)
{
    const int bb = blockIdx.y;
    const int l  = blockIdx.x * 4 + (threadIdx.x >> 6);
    const int lane = threadIdx.x & 63;
    float* row = sc + ((size_t)bb * 4000 + l) * 256;
    const int* tk = tokens + (size_t)(b0 + bb) * 256;
    float4 v = *(const float4*)&row[lane * 4];
    const int4 tv = *(const int4*)&tk[lane * 4];
    if (tv.x == 0) v.x = -1e9f;
    if (tv.y == 0) v.y = -1e9f;
    if (tv.z == 0) v.z = -1e9f;
    if (tv.w == 0) v.w = -1e9f;
    float mx = fmaxf(fmaxf(v.x, v.y), fmaxf(v.z, v.w));
    for (int o = 32; o > 0; o >>= 1) mx = fmaxf(mx, __shfl_xor(mx, o));
    v.x = __expf(v.x - mx); v.y = __expf(v.y - mx);
    v.z = __expf(v.z - mx); v.w = __expf(v.w - mx);
    float s = v.x + v.y + v.z + v.w;
    for (int o = 32; o > 0; o >>= 1) s += __shfl_xor(s, o);
    const float inv = 1.f / s;
    v.x *= inv; v.y *= inv; v.z *= inv; v.w *= inv;
    *(float4*)&row[lane * 4] = v;
}

// ---------------------------------------------------------------------------
// Sparse GCN aggregation: out[l,:] = relu(sum_j adj[l,j]*tmp[j,:] + bias).
// adj ~0.43% dense (+diag). Deterministic ballot compaction, ordered by j.
// grid = 4000 blocks, 256 threads (4 waves scan 1000 cols each).
// ---------------------------------------------------------------------------
__global__ __launch_bounds__(256) void spmm_k(
    const float* __restrict__ adj, const float* __restrict__ tmp,
    const float* __restrict__ bias, float* __restrict__ outp)
{
    const int l = blockIdx.x;
    __shared__ int   idxs[4][256];
    __shared__ float vals[4][256];
    __shared__ int   cnts[4];
    const int t = threadIdx.x;
    const int w = t >> 6, lane = t & 63;
    const float* arow = adj + (size_t)l * 4000;
    int cnt = 0;
    for (int r = 0; r < 16; ++r) {
        const int o = r * 64 + lane;
        const int j = w * 1000 + o;
        const float a = (o < 1000) ? arow[j] : 0.f;
        const unsigned long long mk = __ballot(a != 0.f);
        if (a != 0.f) {
            const int pos = cnt + __popcll(mk & ((1ull << lane) - 1ull));
            if (pos < 256) { idxs[w][pos] = j; vals[w][pos] = a; }
        }
        cnt += __popcll(mk);
    }
    if (lane == 0) cnts[w] = min(cnt, 256);
    __syncthreads();
    const int c0 = t * 2;
    float a0 = 0.f, a1 = 0.f;
    for (int ww = 0; ww < 4; ++ww) {
        const int n = cnts[ww];
        for (int e = 0; e < n; ++e) {
            const float a = vals[ww][e];
            const float2 tv = *(const float2*)&tmp[(size_t)idxs[ww][e] * 512 + c0];
            a0 = fmaf(a, tv.x, a0);
            a1 = fmaf(a, tv.y, a1);
        }
    }
    float2 res;
    res.x = fmaxf(a0 + bias[c0], 0.f);
    res.y = fmaxf(a1 + bias[c0 + 1], 0.f);
    *(float2*)&outp[(size_t)l * 512 + c0] = res;
}

// ---------------------------------------------------------------------------
// Final projection: out[b0+bb, l] = dot(x2[r,:256], w_out) + b_out.
// One wave per row. grid = nb*1000, 256 threads.
// ---------------------------------------------------------------------------
__global__ __launch_bounds__(256) void out_k(
    const float* __restrict__ x2, const float* __restrict__ w_out,
    const float* __restrict__ b_out, float* __restrict__ outp, int b0)
{
    const int r = blockIdx.x * 4 + (threadIdx.x >> 6);
    const int lane = threadIdx.x & 63;
    const float4 xv = *(const float4*)&x2[(size_t)r * 256 + lane * 4];
    const float4 wv = *(const float4*)&w_out[lane * 4];
    float s = xv.x * wv.x + xv.y * wv.y + xv.z * wv.z + xv.w * wv.w;
    for (int o = 32; o > 0; o >>= 1) s += __shfl_xor(s, o);
    if (lane == 0) {
        const int bb = r / 4000, l = r - bb * 4000;
        outp[(size_t)(b0 + bb) * 4000 + l] = s + b_out[0];
    }
}

// ---------------------------------------------------------------------------
extern "C" void kernel_launch(void* const* d_in, const int* in_sizes, int n_in,
                              void* d_out, int out_size, void* d_ws, size_t ws_size,
                              hipStream_t stream)
{
    const int*   tokens    = (const int*)  d_in[0];
    const float* emb       = (const float*)d_in[1];
    const float* w_ih_f    = (const float*)d_in[2];
    const float* w_hh_f    = (const float*)d_in[3];
    const float* b_f       = (const float*)d_in[4];
    const float* w_ih_b    = (const float*)d_in[5];
    const float* w_hh_b    = (const float*)d_in[6];
    const float* b_b       = (const float*)d_in[7];
    const float* attn_w    = (const float*)d_in[8];
    const float* label_emb = (const float*)d_in[9];
    const float* adj       = (const float*)d_in[10];
    const float* gcn_w     = (const float*)d_in[11];
    const float* gcn_b     = (const float*)d_in[12];
    const float* w1        = (const float*)d_in[13];
    const float* b1        = (const float*)d_in[14];
    const float* w2        = (const float*)d_in[15];
    const float* b2        = (const float*)d_in[16];
    const float* w_out     = (const float*)d_in[17];
    const float* b_out     = (const float*)d_in[18];
    float* outp = (float*)d_out;
    float* wsf  = (float*)d_ws;

    // workspace layout (floats)
    const size_t off_gf  = 0;          // gates_f  8192*1024
    const size_t off_gb  = 8388608;    // gates_b  8192*1024
    const size_t off_rnn = 16777216;   // rnn      8192*512
    const size_t off_tmp = 20971520;   // gcn_tmp  4000*512
    const size_t off_go  = 23019520;   // gcn_out  4000*512
    const size_t off_ctr = 25067520;   // contrib  4000*512
    const size_t base_end = 27115520;
    // per-chunk area: NB*4000*(256 + 512 + 512 + 256) = NB*6144000 floats
    const size_t have = ws_size / 4;
    int NB; size_t off_chunk;
    if      (have >= base_end + 4ul * 6144000) { NB = 4; off_chunk = base_end; }
    else if (have >= base_end + 2ul * 6144000) { NB = 2; off_chunk = base_end; }
    else { NB = 2; off_chunk = off_gf; } // overlay dead gates buffers (12.3M < 16.8M)

    float* gates_f = wsf + off_gf;
    float* gates_b = wsf + off_gb;
    float* rnn     = wsf + off_rnn;
    float* gcn_tmp = wsf + off_tmp;
    float* gcn_out = wsf + off_go;
    float* contrib = wsf + off_ctr;
    float* scoresb = wsf + off_chunk;                         // NB*4000*256
    float* attnb   = scoresb + (size_t)NB * 1024000;          // NB*4000*512
    float* x1b     = attnb   + (size_t)NB * 2048000;          // NB*4000*512
    float* x2b     = x1b     + (size_t)NB * 2048000;          // NB*4000*256

    // 1. input projections (embedding gather fused): gates = emb[tok] @ w_ih^T + b
    gemm_k<true, true><<<dim3(8, 128, 1), 256, 0, stream>>>(
        emb, w_ih_f, gates_f, 8192, 1024, 300, 300, 300, 1024,
        0, 0, 0, tokens, b_f, nullptr, 1, 0, 0);
    gemm_k<true, true><<<dim3(8, 128, 1), 256, 0, stream>>>(
        emb, w_ih_b, gates_b, 8192, 1024, 300, 300, 300, 1024,
        0, 0, 0, tokens, b_b, nullptr, 1, 0, 0);

    // 2. biLSTM scan -> rnn [B,S,512]
    lstm_k<<<dim3(32, 2), 1024, 0, stream>>>(gates_f, gates_b, w_hh_f, w_hh_b, rnn);

    // 3. GCN branch (batch independent)
    gemm_k<false, false><<<dim3(4, 63, 1), 256, 0, stream>>>(
        label_emb, gcn_w, gcn_tmp, 4000, 512, 256, 256, 512, 512,
        0, 0, 0, nullptr, nullptr, nullptr, 1, 0, 0);
    spmm_k<<<dim3(4000), 256, 0, stream>>>(adj, gcn_tmp, gcn_b, gcn_out);
    // contrib = gcn_out @ w1[512:1024,:] + b1   (batch-independent half of layer 1)
    gemm_k<false, false><<<dim3(4, 63, 1), 256, 0, stream>>>(
        gcn_out, w1 + (size_t)512 * 512, contrib, 4000, 512, 512, 512, 512, 512,
        0, 0, 0, nullptr, b1, nullptr, 1, 0, 0);

    // 4. attention + MLP head, chunked over batch
    for (int b0 = 0; b0 < 32; b0 += NB) {
        const int nb = (32 - b0 < NB) ? (32 - b0) : NB;
        // scores[bb,l,s] = attn_w[l,:] . rnn[b0+bb,s,:]
        gemm_k<true, false><<<dim3(2, 63, nb), 256, 0, stream>>>(
            attn_w, rnn + (size_t)b0 * 131072, scoresb, 4000, 256, 512, 512, 512, 256,
            0, 131072, 1024000, nullptr, nullptr, nullptr, 1, 0, 0);
        softmax_k<<<dim3(1000, nb), 256, 0, stream>>>(scoresb, tokens, b0);
        // attn_out[bb,l,h] = probs[bb,l,:] @ rnn[b0+bb,:,h]
        gemm_k<false, false><<<dim3(4, 63, nb), 256, 0, stream>>>(
            scoresb, rnn + (size_t)b0 * 131072, attnb, 4000, 512, 256, 256, 512, 512,
            1024000, 131072, 2048000, nullptr, nullptr, nullptr, 1, 0, 0);
        // x1 = relu(attn_out @ w1[0:512,:] + contrib[l,:])
        gemm_k<false, false><<<dim3(4, (nb * 4000 + 63) / 64, 1), 256, 0, stream>>>(
            attnb, w1, x1b, nb * 4000, 512, 512, 512, 512, 512,
            0, 0, 0, nullptr, nullptr, contrib, 4000, 512, 1);
        // x2 = relu(x1 @ w2 + b2)
        gemm_k<false, false><<<dim3(2, (nb * 4000 + 63) / 64, 1), 256, 0, stream>>>(
            x1b, w2, x2b, nb * 4000, 256, 512, 512, 256, 256,
            0, 0, 0, nullptr, b2, nullptr, 1, 0, 1);
        // out = x2 @ w_out + b_out
        out_k<<<dim3(nb * 1000), 256, 0, stream>>>(x2b, w_out, b_out, outp, b0);
    }
}

// Round 2
// 6748.501 us; speedup vs baseline: 1.8018x; 1.8018x over previous
//
#include <hip/hip_runtime.h>
#include <hip/hip_bf16.h>
#include <math.h>

// Problem constants
// B=32 S=256 E=300 H=256(4H=1024) L=4000 D=256 G=512 V=50000 LIN1=512 LIN2=256, 2H=512

// ---------------------------------------------------------------------------
// Generic tiled fp32 GEMM: C[M,N] = A[M,K] * B + epilogue
//   BT=true : B is [N][K] row-major ; BT=false: B is [K][N] row-major
//   GATHER  : A row m comes from A + tok[m]*lda  (embedding gather)
// Tile: BM=64, BN=128, BK=16, 256 threads, each thread 4(m)x8(n)
// ---------------------------------------------------------------------------
template<bool BT, bool GATHER>
__global__ __launch_bounds__(256) void gemm_k(
    const float* __restrict__ A, const float* __restrict__ Bm, float* __restrict__ C,
    int M, int N, int K, int lda, int ldb, int ldc,
    long abs_, long bbs_, long cbs_,
    const int* __restrict__ tok,
    const float* __restrict__ bias,
    const float* __restrict__ addrow, int addmod, int ldadd,
    int do_relu)
{
    const int tid = threadIdx.x;
    const int tx = tid & 15;        // n dim: 16 threads x 8 cols
    const int ty = tid >> 4;        // m dim: 16 threads x 4 rows
    const int n0 = blockIdx.x * 128;
    const int m0 = blockIdx.y * 64;
    const int z  = blockIdx.z;
    A  += (size_t)z * abs_;
    Bm += (size_t)z * bbs_;
    C  += (size_t)z * cbs_;

    __shared__ float As[16][68];
    __shared__ float Bs[16][132];

    float acc[4][8];
#pragma unroll
    for (int i = 0; i < 4; ++i)
#pragma unroll
        for (int j = 0; j < 8; ++j) acc[i][j] = 0.f;

    const int ksteps = (K + 15) / 16;
    for (int kt = 0; kt < ksteps; ++kt) {
        const int k0 = kt * 16;
#pragma unroll
        for (int j = 0; j < 4; ++j) {
            int e  = tid + j * 256;
            int kk = e & 15;
            int m  = e >> 4;
            int gm = m0 + m, gk = k0 + kk;
            float v = 0.f;
            if (gm < M && gk < K) {
                size_t rb;
                if (GATHER) rb = (size_t)tok[gm] * lda;
                else        rb = (size_t)gm * lda;
                v = A[rb + gk];
            }
            As[kk][m] = v;
        }
#pragma unroll
        for (int j = 0; j < 8; ++j) {
            int e = tid + j * 256;
            if (BT) {
                int kk = e & 15;
                int n  = e >> 4;
                int gn = n0 + n, gk = k0 + kk;
                Bs[kk][n] = (gn < N && gk < K) ? Bm[(size_t)gn * ldb + gk] : 0.f;
            } else {
                int n  = e & 127;
                int kk = e >> 7;
                int gn = n0 + n, gk = k0 + kk;
                Bs[kk][n] = (gn < N && gk < K) ? Bm[(size_t)gk * ldb + gn] : 0.f;
            }
        }
        __syncthreads();
#pragma unroll
        for (int kk = 0; kk < 16; ++kk) {
            const float4 av  = *(const float4*)&As[kk][ty * 4];
            const float4 b0v = *(const float4*)&Bs[kk][tx * 8];
            const float4 b1v = *(const float4*)&Bs[kk][tx * 8 + 4];
            const float a_[4] = {av.x, av.y, av.z, av.w};
            const float b_[8] = {b0v.x, b0v.y, b0v.z, b0v.w, b1v.x, b1v.y, b1v.z, b1v.w};
#pragma unroll
            for (int i = 0; i < 4; ++i)
#pragma unroll
                for (int j = 0; j < 8; ++j) acc[i][j] = fmaf(a_[i], b_[j], acc[i][j]);
        }
        __syncthreads();
    }

#pragma unroll
    for (int i = 0; i < 4; ++i) {
        const int gm = m0 + ty * 4 + i;
        if (gm >= M) continue;
        const float* addp = addrow ? (addrow + (size_t)(gm % addmod) * ldadd) : nullptr;
#pragma unroll
        for (int j = 0; j < 8; ++j) {
            const int gn = n0 + tx * 8 + j;
            if (gn >= N) continue;
            float v = acc[i][j];
            if (bias) v += bias[gn];
            if (addp) v += addp[gn];
            if (do_relu) v = fmaxf(v, 0.f);
            C[(size_t)gm * ldc + gn] = v;
        }
    }
}

// ---------------------------------------------------------------------------
// Register-resident biLSTM scan.
// grid = (64 pairs, 4 quarters), 1024 threads. Pair p = (batch b=p>>1, dir=p&1).
// Block (p,q) owns hidden units [64q, 64q+64): 256 gate rows of W held in
// registers (64 floats/thread, loaded once). Per step: h staged from a
// parity-double-buffered global buffer (agent-scope loads, cross-XCD safe),
// 64-FMA dot per thread, 4-lane shfl reduce, gate exchange via LDS, 64 writer
// threads update c/h and publish the h-slice; device-scope counter syncs the
// 4 partner blocks. Co-residency: 256 blocks <= 1/CU * 256 CUs => no deadlock.
// ---------------------------------------------------------------------------
__global__ __launch_bounds__(1024) void lstm_reg_k(
    const float* __restrict__ gxf, const float* __restrict__ gxb,
    const float* __restrict__ whf, const float* __restrict__ whb,
    float* __restrict__ rnn, float* hbuf, int* cnt)
{
    const int p = blockIdx.x;          // pair
    const int q = blockIdx.y;          // quarter
    const int b = p >> 1, dir = p & 1;
    const float* xg = dir ? gxb : gxf;
    const float* W  = dir ? whb : whf;
    const int tid = threadIdx.x;
    const int row = tid >> 2;          // 0..255 block-local gate row
    const int ks  = tid & 3;           // k-slice (64 floats each)
    const int gt  = row >> 6;          // gate type 0..3 (i,f,g,o)
    const int ul  = row & 63;          // unit within slice
    const int grow = gt * 256 + q * 64 + ul;   // global gate row in [0,1024)

    // W row slice -> 16 float4 registers (64 VGPRs), loaded once
    float4 w[16];
    {
        const float4* wp = (const float4*)(W + (size_t)grow * 256 + ks * 64);
#pragma unroll
        for (int i = 0; i < 16; ++i) w[i] = wp[i];
    }

    __shared__ float h_lds[4 * 68];    // skewed: slice ks at offset ks*68 (bank spread)
    __shared__ float xg_lds[256];
    __shared__ float g_lds[256];

    float* hb0 = hbuf + (size_t)p * 256;            // parity 0
    float* hb1 = hbuf + (size_t)(64 + p) * 256;     // parity 1
    int* cp = cnt + p;

    float c = 0.f;                      // live in tid<64 (unit owners)
    const size_t xgb = (size_t)b * 256; // row base for xg

    for (int st = 0; st < 256; ++st) {
        const int ts = dir ? 255 - st : st;
        // stage this step's x-gate slice (independent of partners -> overlaps spin)
        if (tid < 256) {
            const int g2 = (tid >> 6) * 256 + q * 64 + (tid & 63);
            xg_lds[tid] = xg[(xgb + ts) * 1024 + g2];
        }
        if (st > 0 && tid == 0) {
            while (__hip_atomic_load(cp, __ATOMIC_ACQUIRE, __HIP_MEMORY_SCOPE_AGENT) < 4 * st) {}
        }
        __syncthreads();   // B1: partners' h[st-1] published; xg staged
        if (tid < 256) {
            float hv = 0.f;
            if (st > 0) {
                const float* src = ((st & 1) ? hb0 : hb1);  // read parity (st-1)&1
                hv = __hip_atomic_load(&src[tid], __ATOMIC_RELAXED, __HIP_MEMORY_SCOPE_AGENT);
            }
            h_lds[(tid >> 6) * 68 + (tid & 63)] = hv;
        }
        __syncthreads();   // B2: h_lds ready
        // 64-FMA partial dot on this thread's k-slice
        float acc = 0.f;
        {
            const float4* hp = (const float4*)&h_lds[ks * 68];
#pragma unroll
            for (int i = 0; i < 16; ++i) {
                const float4 hv = hp[i];
                acc = fmaf(w[i].x, hv.x, acc);
                acc = fmaf(w[i].y, hv.y, acc);
                acc = fmaf(w[i].z, hv.z, acc);
                acc = fmaf(w[i].w, hv.w, acc);
            }
        }
        acc += __shfl_xor(acc, 1);
        acc += __shfl_xor(acc, 2);
        if (ks == 0) g_lds[row] = acc + xg_lds[row];
        __syncthreads();   // B3: gates ready
        if (tid < 64) {
            const float gi = g_lds[tid];
            const float gf = g_lds[64 + tid];
            const float gg = g_lds[128 + tid];
            const float go = g_lds[192 + tid];
            const float si = 1.f / (1.f + expf(-gi));
            const float sf = 1.f / (1.f + expf(-gf));
            const float so = 1.f / (1.f + expf(-go));
            c = sf * c + si * tanhf(gg);
            const float hn = so * tanhf(c);
            const int u = q * 64 + tid;
            float* dst = ((st & 1) ? hb1 : hb0);    // write parity st&1
            __hip_atomic_store(&dst[u], hn, __ATOMIC_RELAXED, __HIP_MEMORY_SCOPE_AGENT);
            rnn[(xgb + ts) * 512 + (size_t)dir * 256 + u] = hn;
        }
        __syncthreads();   // B4: vmcnt(0) drain of stores before release
        if (tid == 0) {
            __hip_atomic_fetch_add(cp, 1, __ATOMIC_RELEASE, __HIP_MEMORY_SCOPE_AGENT);
        }
    }
}

__global__ void init_cnt_k(int* cnt) {
    if (threadIdx.x < 64) cnt[threadIdx.x] = 0;
}

// ---------------------------------------------------------------------------
// Masked softmax over s (256) per (bb,l) row, in place. grid=(1000, nb), 256 thr.
// ---------------------------------------------------------------------------
__global__ __launch_bounds__(256) void softmax_k(
    float* __restrict__ sc, const int* __restrict__ tokens, int b0)
{
    const int bb = blockIdx.y;
    const int l  = blockIdx.x * 4 + (threadIdx.x >> 6);
    const int lane = threadIdx.x & 63;
    float* row = sc + ((size_t)bb * 4000 + l) * 256;
    const int* tk = tokens + (size_t)(b0 + bb) * 256;
    float4 v = *(const float4*)&row[lane * 4];
    const int4 tv = *(const int4*)&tk[lane * 4];
    if (tv.x == 0) v.x = -1e9f;
    if (tv.y == 0) v.y = -1e9f;
    if (tv.z == 0) v.z = -1e9f;
    if (tv.w == 0) v.w = -1e9f;
    float mx = fmaxf(fmaxf(v.x, v.y), fmaxf(v.z, v.w));
    for (int o = 32; o > 0; o >>= 1) mx = fmaxf(mx, __shfl_xor(mx, o));
    v.x = __expf(v.x - mx); v.y = __expf(v.y - mx);
    v.z = __expf(v.z - mx); v.w = __expf(v.w - mx);
    float s = v.x + v.y + v.z + v.w;
    for (int o = 32; o > 0; o >>= 1) s += __shfl_xor(s, o);
    const float inv = 1.f / s;
    v.x *= inv; v.y *= inv; v.z *= inv; v.w *= inv;
    *(float4*)&row[lane * 4] = v;
}

// ---------------------------------------------------------------------------
// Sparse GCN aggregation: out[l,:] = relu(sum_j adj[l,j]*tmp[j,:] + bias).
// ---------------------------------------------------------------------------
__global__ __launch_bounds__(256) void spmm_k(
    const float* __restrict__ adj, const float* __restrict__ tmp,
    const float* __restrict__ bias, float* __restrict__ outp)
{
    const int l = blockIdx.x;
    __shared__ int   idxs[4][256];
    __shared__ float vals[4][256];
    __shared__ int   cnts[4];
    const int t = threadIdx.x;
    const int w = t >> 6, lane = t & 63;
    const float* arow = adj + (size_t)l * 4000;
    int cnt = 0;
    for (int r = 0; r < 16; ++r) {
        const int o = r * 64 + lane;
        const int j = w * 1000 + o;
        const float a = (o < 1000) ? arow[j] : 0.f;
        const unsigned long long mk = __ballot(a != 0.f);
        if (a != 0.f) {
            const int pos = cnt + __popcll(mk & ((1ull << lane) - 1ull));
            if (pos < 256) { idxs[w][pos] = j; vals[w][pos] = a; }
        }
        cnt += __popcll(mk);
    }
    if (lane == 0) cnts[w] = min(cnt, 256);
    __syncthreads();
    const int c0 = t * 2;
    float a0 = 0.f, a1 = 0.f;
    for (int ww = 0; ww < 4; ++ww) {
        const int n = cnts[ww];
        for (int e = 0; e < n; ++e) {
            const float a = vals[ww][e];
            const float2 tv = *(const float2*)&tmp[(size_t)idxs[ww][e] * 512 + c0];
            a0 = fmaf(a, tv.x, a0);
            a1 = fmaf(a, tv.y, a1);
        }
    }
    float2 res;
    res.x = fmaxf(a0 + bias[c0], 0.f);
    res.y = fmaxf(a1 + bias[c0 + 1], 0.f);
    *(float2*)&outp[(size_t)l * 512 + c0] = res;
}

// ---------------------------------------------------------------------------
// Final projection: out[b0+bb, l] = dot(x2[r,:256], w_out) + b_out.
// ---------------------------------------------------------------------------
__global__ __launch_bounds__(256) void out_k(
    const float* __restrict__ x2, const float* __restrict__ w_out,
    const float* __restrict__ b_out, float* __restrict__ outp, int b0)
{
    const int r = blockIdx.x * 4 + (threadIdx.x >> 6);
    const int lane = threadIdx.x & 63;
    const float4 xv = *(const float4*)&x2[(size_t)r * 256 + lane * 4];
    const float4 wv = *(const float4*)&w_out[lane * 4];
    float s = xv.x * wv.x + xv.y * wv.y + xv.z * wv.z + xv.w * wv.w;
    for (int o = 32; o > 0; o >>= 1) s += __shfl_xor(s, o);
    if (lane == 0) {
        const int bb = r / 4000, l = r - bb * 4000;
        outp[(size_t)(b0 + bb) * 4000 + l] = s + b_out[0];
    }
}

// ---------------------------------------------------------------------------
extern "C" void kernel_launch(void* const* d_in, const int* in_sizes, int n_in,
                              void* d_out, int out_size, void* d_ws, size_t ws_size,
                              hipStream_t stream)
{
    const int*   tokens    = (const int*)  d_in[0];
    const float* emb       = (const float*)d_in[1];
    const float* w_ih_f    = (const float*)d_in[2];
    const float* w_hh_f    = (const float*)d_in[3];
    const float* b_f       = (const float*)d_in[4];
    const float* w_ih_b    = (const float*)d_in[5];
    const float* w_hh_b    = (const float*)d_in[6];
    const float* b_b       = (const float*)d_in[7];
    const float* attn_w    = (const float*)d_in[8];
    const float* label_emb = (const float*)d_in[9];
    const float* adj       = (const float*)d_in[10];
    const float* gcn_w     = (const float*)d_in[11];
    const float* gcn_b     = (const float*)d_in[12];
    const float* w1        = (const float*)d_in[13];
    const float* b1        = (const float*)d_in[14];
    const float* w2        = (const float*)d_in[15];
    const float* b2        = (const float*)d_in[16];
    const float* w_out     = (const float*)d_in[17];
    const float* b_out     = (const float*)d_in[18];
    float* outp = (float*)d_out;
    float* wsf  = (float*)d_ws;

    // workspace layout (floats)
    const size_t off_gf  = 0;          // gates_f  8192*1024
    const size_t off_gb  = 8388608;    // gates_b  8192*1024
    const size_t off_rnn = 16777216;   // rnn      8192*512
    const size_t off_tmp = 20971520;   // gcn_tmp  4000*512  (lstm hbuf/cnt overlay, dead by GCN time)
    const size_t off_go  = 23019520;   // gcn_out  4000*512
    const size_t off_ctr = 25067520;   // contrib  4000*512
    const size_t base_end = 27115520;
    const size_t have = ws_size / 4;
    int NB; size_t off_chunk;
    if      (have >= base_end + 4ul * 6144000) { NB = 4; off_chunk = base_end; }
    else if (have >= base_end + 2ul * 6144000) { NB = 2; off_chunk = base_end; }
    else { NB = 2; off_chunk = off_gf; } // overlay dead gates buffers

    float* gates_f = wsf + off_gf;
    float* gates_b = wsf + off_gb;
    float* rnn     = wsf + off_rnn;
    float* gcn_tmp = wsf + off_tmp;
    float* gcn_out = wsf + off_go;
    float* contrib = wsf + off_ctr;
    // lstm sync state overlays gcn_tmp region (2048000 floats >> 32768+64 needed)
    float* hbuf    = wsf + off_tmp;                  // [2][64][256]
    int*   cnt     = (int*)(wsf + off_tmp + 32768);  // [64]
    float* scoresb = wsf + off_chunk;
    float* attnb   = scoresb + (size_t)NB * 1024000;
    float* x1b     = attnb   + (size_t)NB * 2048000;
    float* x2b     = x1b     + (size_t)NB * 2048000;

    // 0. zero lstm sync counters (graph-replay safe)
    init_cnt_k<<<1, 64, 0, stream>>>(cnt);

    // 1. input projections (embedding gather fused): gates = emb[tok] @ w_ih^T + b
    gemm_k<true, true><<<dim3(8, 128, 1), 256, 0, stream>>>(
        emb, w_ih_f, gates_f, 8192, 1024, 300, 300, 300, 1024,
        0, 0, 0, tokens, b_f, nullptr, 1, 0, 0);
    gemm_k<true, true><<<dim3(8, 128, 1), 256, 0, stream>>>(
        emb, w_ih_b, gates_b, 8192, 1024, 300, 300, 300, 1024,
        0, 0, 0, tokens, b_b, nullptr, 1, 0, 0);

    // 2. biLSTM scan -> rnn [B,S,512]  (register-resident W, 256 blocks)
    lstm_reg_k<<<dim3(64, 4), 1024, 0, stream>>>(
        gates_f, gates_b, w_hh_f, w_hh_b, rnn, hbuf, cnt);

    // 3. GCN branch (batch independent)
    gemm_k<false, false><<<dim3(4, 63, 1), 256, 0, stream>>>(
        label_emb, gcn_w, gcn_tmp, 4000, 512, 256, 256, 512, 512,
        0, 0, 0, nullptr, nullptr, nullptr, 1, 0, 0);
    spmm_k<<<dim3(4000), 256, 0, stream>>>(adj, gcn_tmp, gcn_b, gcn_out);
    gemm_k<false, false><<<dim3(4, 63, 1), 256, 0, stream>>>(
        gcn_out, w1 + (size_t)512 * 512, contrib, 4000, 512, 512, 512, 512, 512,
        0, 0, 0, nullptr, b1, nullptr, 1, 0, 0);

    // 4. attention + MLP head, chunked over batch
    for (int b0 = 0; b0 < 32; b0 += NB) {
        const int nb = (32 - b0 < NB) ? (32 - b0) : NB;
        gemm_k<true, false><<<dim3(2, 63, nb), 256, 0, stream>>>(
            attn_w, rnn + (size_t)b0 * 131072, scoresb, 4000, 256, 512, 512, 512, 256,
            0, 131072, 1024000, nullptr, nullptr, nullptr, 1, 0, 0);
        softmax_k<<<dim3(1000, nb), 256, 0, stream>>>(scoresb, tokens, b0);
        gemm_k<false, false><<<dim3(4, 63, nb), 256, 0, stream>>>(
            scoresb, rnn + (size_t)b0 * 131072, attnb, 4000, 512, 256, 256, 512, 512,
            1024000, 131072, 2048000, nullptr, nullptr, nullptr, 1, 0, 0);
        gemm_k<false, false><<<dim3(4, (nb * 4000 + 63) / 64, 1), 256, 0, stream>>>(
            attnb, w1, x1b, nb * 4000, 512, 512, 512, 512, 512,
            0, 0, 0, nullptr, nullptr, contrib, 4000, 512, 1);
        gemm_k<false, false><<<dim3(2, (nb * 4000 + 63) / 64, 1), 256, 0, stream>>>(
            x1b, w2, x2b, nb * 4000, 256, 512, 512, 256, 256,
            0, 0, 0, nullptr, b2, nullptr, 1, 0, 1);
        out_k<<<dim3(nb * 1000), 256, 0, stream>>>(x2b, w_out, b_out, outp, b0);
    }
}